// Round 1
// baseline (367.948 us; speedup 1.0000x reference)
//
#include <hip/hip_runtime.h>

typedef unsigned short u16;
typedef __bf16 bf16x8 __attribute__((ext_vector_type(8)));
typedef float  f32x4  __attribute__((ext_vector_type(4)));

#define DIM   1024
#define SEQ   2048
#define NH    16
#define HD    64
#define NBATCH 2
#define MTOK  (NBATCH*SEQ)   // 4096

// ---------- helpers ----------

__device__ __forceinline__ u16 f2bf(float f) {
  unsigned u = __float_as_uint(f);
  unsigned r = (u + 0x7FFFu + ((u >> 16) & 1u)) >> 16;  // RNE
  return (u16)r;
}

// async global->LDS, 16B per lane. lds dest must be wave-uniform base (+lane*16 by HW).
__device__ __forceinline__ void gload16(const void* g, void* lds_uniform) {
  __builtin_amdgcn_global_load_lds(
      (__attribute__((address_space(1))) void*)(size_t)g,
      (__attribute__((address_space(3))) void*)lds_uniform,
      16, 0, 0);
}

// ---------- fp32 -> bf16 convert (8 elems/thread, grid sized exactly) ----------

typedef unsigned short u16x8 __attribute__((ext_vector_type(8)));

__global__ __launch_bounds__(256) void cvt_bf16(const float* __restrict__ src,
                                                u16* __restrict__ dst) {
  size_t i = ((size_t)blockIdx.x * 256 + threadIdx.x) * 8;
  float4 a = *(const float4*)(src + i);
  float4 b = *(const float4*)(src + i + 4);
  u16x8 o;
  o[0] = f2bf(a.x); o[1] = f2bf(a.y); o[2] = f2bf(a.z); o[3] = f2bf(a.w);
  o[4] = f2bf(b.x); o[5] = f2bf(b.y); o[6] = f2bf(b.z); o[7] = f2bf(b.w);
  *(u16x8*)(dst + i) = o;
}

// ---------- GEMM core: C[m,n] = sum_k A[m,k]*W[n,k], 128x128 tile, BK=32 ----------
// A: [4096,1024] bf16 row-major; W: [1024,1024] bf16 row-major (nn.Linear W, y = x @ W^T)

__device__ __forceinline__ void gemm128_core(const u16* __restrict__ A,
                                             const u16* __restrict__ W,
                                             u16* lds, f32x4 (&acc)[4][4]) {
  const int K = 1024;
  const int tid = threadIdx.x;
  const int wave = tid >> 6, lane = tid & 63;
  const int quad = lane >> 4, l15 = lane & 15;
  const int warp_m = wave >> 1, warp_n = wave & 1;
  const int bm = blockIdx.y, bn = blockIdx.x;

  // staging: 512 16B-chunks per matrix; chunk c -> row c>>2, kchunk (c&3)*8
  const int c0 = wave * 128 + lane, c1 = c0 + 64;
  const u16* Ag0 = A + (size_t)(bm * 128 + (c0 >> 2)) * K + (c0 & 3) * 8;
  const u16* Ag1 = A + (size_t)(bm * 128 + (c1 >> 2)) * K + (c1 & 3) * 8;
  const u16* Wg0 = W + (size_t)(bn * 128 + (c0 >> 2)) * K + (c0 & 3) * 8;
  const u16* Wg1 = W + (size_t)(bn * 128 + (c1 >> 2)) * K + (c1 & 3) * 8;
  u16* lA0 = lds + (wave * 2 + 0) * 512;
  u16* lA1 = lds + (wave * 2 + 1) * 512;
  u16* lB0 = lds + 4096 + (wave * 2 + 0) * 512;
  u16* lB1 = lds + 4096 + (wave * 2 + 1) * 512;

  for (int k0 = 0; k0 < K; k0 += 32) {
    gload16(Ag0 + k0, lA0);
    gload16(Ag1 + k0, lA1);
    gload16(Wg0 + k0, lB0);
    gload16(Wg1 + k0, lB1);
    __syncthreads();   // drains vmcnt (global_load_lds) + barrier

    bf16x8 af[4], bfr[4];
#pragma unroll
    for (int i = 0; i < 4; ++i) {
      af[i]  = *(const bf16x8*)(lds + (warp_m * 64 + i * 16 + l15) * 32 + quad * 8);
      bfr[i] = *(const bf16x8*)(lds + 4096 + (warp_n * 64 + i * 16 + l15) * 32 + quad * 8);
    }
#pragma unroll
    for (int i = 0; i < 4; ++i)
#pragma unroll
      for (int j = 0; j < 4; ++j)
        acc[i][j] = __builtin_amdgcn_mfma_f32_16x16x32_bf16(af[i], bfr[j], acc[i][j], 0, 0, 0);
    __syncthreads();   // protect LDS before next stage
  }
}

// QKV projection: z=0 -> Q [B,H,S,64], z=1 -> K [B,H,S,64], z=2 -> V^T [B,H,64,S]
__global__ __launch_bounds__(256) void gemm_qkv(
    const u16* __restrict__ qb, const u16* __restrict__ kb, const u16* __restrict__ vb,
    const u16* __restrict__ wq, const u16* __restrict__ wk, const u16* __restrict__ wv,
    u16* __restrict__ Qo, u16* __restrict__ Ko, u16* __restrict__ Vt) {
  __shared__ __align__(16) u16 lds[8192];
  const int z = blockIdx.z;
  const u16* A = (z == 0) ? qb : (z == 1) ? kb : vb;
  const u16* W = (z == 0) ? wq : (z == 1) ? wk : wv;
  f32x4 acc[4][4] = {};
  gemm128_core(A, W, lds, acc);

  const int tid = threadIdx.x;
  const int wave = tid >> 6, lane = tid & 63;
  const int quad = lane >> 4, l15 = lane & 15;
  const int warp_m = wave >> 1, warp_n = wave & 1;
  const int bm = blockIdx.y, bn = blockIdx.x;
#pragma unroll
  for (int i = 0; i < 4; ++i)
#pragma unroll
    for (int j = 0; j < 4; ++j)
#pragma unroll
      for (int r = 0; r < 4; ++r) {
        int m = bm * 128 + warp_m * 64 + i * 16 + quad * 4 + r;   // token
        int n = bn * 128 + warp_n * 64 + j * 16 + l15;            // out dim
        int b = m >> 11, s = m & 2047, h = n >> 6, d = n & 63;
        u16 val = f2bf(acc[i][j][r]);
        if (z == 2)
          Vt[((size_t)(b * NH + h) * HD + d) * SEQ + s] = val;
        else {
          u16* O = z ? Ko : Qo;
          O[((size_t)(b * NH + h) * SEQ + s) * HD + d] = val;
        }
      }
}

// output projection: fp32 out = AO @ wo^T
__global__ __launch_bounds__(256) void gemm_out(
    const u16* __restrict__ A, const u16* __restrict__ W, float* __restrict__ Out) {
  __shared__ __align__(16) u16 lds[8192];
  f32x4 acc[4][4] = {};
  gemm128_core(A, W, lds, acc);

  const int tid = threadIdx.x;
  const int wave = tid >> 6, lane = tid & 63;
  const int quad = lane >> 4, l15 = lane & 15;
  const int warp_m = wave >> 1, warp_n = wave & 1;
  const int bm = blockIdx.y, bn = blockIdx.x;
#pragma unroll
  for (int i = 0; i < 4; ++i)
#pragma unroll
    for (int j = 0; j < 4; ++j)
#pragma unroll
      for (int r = 0; r < 4; ++r) {
        int m = bm * 128 + warp_m * 64 + i * 16 + quad * 4 + r;
        int n = bn * 128 + warp_n * 64 + j * 16 + l15;
        Out[(size_t)m * DIM + n] = acc[i][j][r];
      }
}

// ---------- flash attention (causal), one block = (64 q-rows, one b*h) ----------
// Q,K: [B,H,S,64] bf16; Vt: [B,H,64,S] bf16; out AO: [B,S,H*64] bf16

__global__ __launch_bounds__(256) void attn_kernel(
    const u16* __restrict__ Q, const u16* __restrict__ K,
    const u16* __restrict__ Vt, u16* __restrict__ O) {
  __shared__ __align__(16) u16 Kl[64 * 64];     // [key][d]
  __shared__ __align__(16) u16 Vl[64 * 64];     // [d][key]  (V transposed)
  __shared__ __align__(16) u16 Pl[4][16 * 64];  // per-wave P: [q][key]

  const int tid = threadIdx.x;
  const int wave = tid >> 6, lane = tid & 63;
  const int quad = lane >> 4, l15 = lane & 15;
  const int qt = blockIdx.x, bh = blockIdx.y;
  const int b = bh >> 4, h = bh & 15;

  // Q fragments, A-operand layout: m=l15, k=quad*8+j (+32 for second frag)
  const u16* qbase = Q + ((size_t)bh * SEQ + qt * 64 + wave * 16 + l15) * HD + quad * 8;
  bf16x8 qf0 = *(const bf16x8*)(qbase);
  bf16x8 qf1 = *(const bf16x8*)(qbase + 32);

  f32x4 o[4] = {};
  float l_sum[4] = {0.f, 0.f, 0.f, 0.f};
  float m_old[4];
#pragma unroll
  for (int r = 0; r < 4; ++r) m_old[r] = -__builtin_inff();

  const int c0 = wave * 128 + lane, c1 = c0 + 64;
  const u16* Ksrc = K + (size_t)bh * SEQ * HD;
  const u16* Vsrc = Vt + (size_t)bh * HD * SEQ;
  u16* lK0 = Kl + (wave * 2 + 0) * 512;
  u16* lK1 = Kl + (wave * 2 + 1) * 512;
  u16* lV0 = Vl + (wave * 2 + 0) * 512;
  u16* lV1 = Vl + (wave * 2 + 1) * 512;

  for (int kt = 0; kt <= qt; ++kt) {
    // K tile: contiguous 8KB
    gload16(Ksrc + (size_t)kt * 64 * HD + c0 * 8, lK0);
    gload16(Ksrc + (size_t)kt * 64 * HD + c1 * 8, lK1);
    // V^T tile: 64 rows of 128B (stride SEQ)
    gload16(Vsrc + (size_t)(c0 >> 3) * SEQ + kt * 64 + (c0 & 7) * 8, lV0);
    gload16(Vsrc + (size_t)(c1 >> 3) * SEQ + kt * 64 + (c1 & 7) * 8, lV1);
    __syncthreads();

    // S = Q K^T  (4 frags of 16 keys)
    f32x4 s[4];
#pragma unroll
    for (int kn = 0; kn < 4; ++kn) {
      const u16* kb = Kl + (kn * 16 + l15) * HD + quad * 8;
      bf16x8 k0 = *(const bf16x8*)(kb);
      bf16x8 k1 = *(const bf16x8*)(kb + 32);
      f32x4 z = {};
      z = __builtin_amdgcn_mfma_f32_16x16x32_bf16(qf0, k0, z, 0, 0, 0);
      z = __builtin_amdgcn_mfma_f32_16x16x32_bf16(qf1, k1, z, 0, 0, 0);
      s[kn] = z;
    }

    const bool diag = (kt == qt);
#pragma unroll
    for (int r = 0; r < 4; ++r) {
      const int ql = wave * 16 + quad * 4 + r;  // q row local to 64-tile
      float mr = -__builtin_inff();
#pragma unroll
      for (int kn = 0; kn < 4; ++kn) {
        float v = s[kn][r] * 0.125f;            // 1/sqrt(64)
        if (diag && (kn * 16 + l15 > ql)) v = -__builtin_inff();
        s[kn][r] = v;
        mr = fmaxf(mr, v);
      }
      mr = fmaxf(mr, __shfl_xor(mr, 1));
      mr = fmaxf(mr, __shfl_xor(mr, 2));
      mr = fmaxf(mr, __shfl_xor(mr, 4));
      mr = fmaxf(mr, __shfl_xor(mr, 8));
      float mnew = fmaxf(m_old[r], mr);
      float alpha = __expf(m_old[r] - mnew);    // 0 on first tile (m_old=-inf)
      m_old[r] = mnew;
      float rs = 0.f;
#pragma unroll
      for (int kn = 0; kn < 4; ++kn) {
        float p = __expf(s[kn][r] - mnew);      // masked -> exp(-inf)=0
        s[kn][r] = p;
        rs += p;
      }
      rs += __shfl_xor(rs, 1);
      rs += __shfl_xor(rs, 2);
      rs += __shfl_xor(rs, 4);
      rs += __shfl_xor(rs, 8);
      l_sum[r] = l_sum[r] * alpha + rs;
#pragma unroll
      for (int n = 0; n < 4; ++n) o[n][r] *= alpha;
      // P: C-layout -> LDS (q-major) for A-operand reload
#pragma unroll
      for (int kn = 0; kn < 4; ++kn)
        Pl[wave][(quad * 4 + r) * 64 + kn * 16 + l15] = f2bf(s[kn][r]);
    }
    __syncthreads();

    // O += P V   (A = P [16q x 64k], B = V [64k x 64d] via Vt LDS)
#pragma unroll
    for (int kk = 0; kk < 2; ++kk) {
      bf16x8 pf = *(const bf16x8*)(Pl[wave] + l15 * 64 + kk * 32 + quad * 8);
#pragma unroll
      for (int n = 0; n < 4; ++n) {
        bf16x8 vf = *(const bf16x8*)(Vl + (n * 16 + l15) * HD + kk * 32 + quad * 8);
        o[n] = __builtin_amdgcn_mfma_f32_16x16x32_bf16(pf, vf, o[n], 0, 0, 0);
      }
    }
    __syncthreads();
  }

  // epilogue: O /= l, write [b, s, h*64+d] bf16
#pragma unroll
  for (int r = 0; r < 4; ++r) {
    float inv = 1.f / l_sum[r];
    int srow = qt * 64 + wave * 16 + quad * 4 + r;
#pragma unroll
    for (int n = 0; n < 4; ++n) {
      int col = h * HD + n * 16 + l15;
      O[((size_t)b * SEQ + srow) * DIM + col] = f2bf(o[n][r] * inv);
    }
  }
}

// ---------- launch ----------

extern "C" void kernel_launch(void* const* d_in, const int* in_sizes, int n_in,
                              void* d_out, int out_size, void* d_ws, size_t ws_size,
                              hipStream_t stream) {
  (void)in_sizes; (void)n_in; (void)out_size; (void)ws_size;
  const float* q  = (const float*)d_in[0];
  const float* k  = (const float*)d_in[1];
  const float* v  = (const float*)d_in[2];
  const float* wq = (const float*)d_in[3];
  const float* wk = (const float*)d_in[4];
  const float* wv = (const float*)d_in[5];
  const float* wo = (const float*)d_in[6];

  u16* ws = (u16*)d_ws;
  const size_t EL = 1u << 20;  // 1M elems
  u16* QB = ws + 0 * EL;   // bf16 q        [4096,1024]
  u16* KB = ws + 4 * EL;   // bf16 k
  u16* VB = ws + 8 * EL;   // bf16 v
  u16* WQ = ws + 12 * EL;  // bf16 weights  [1024,1024]
  u16* WK = ws + 13 * EL;
  u16* WV = ws + 14 * EL;
  u16* WO = ws + 15 * EL;
  u16* Qw = ws + 16 * EL;  // Q  [B,H,S,64]
  u16* Kw = ws + 20 * EL;  // K  [B,H,S,64]
  u16* Vtw = ws + 24 * EL; // V^T [B,H,64,S]
  u16* AO = ws + 28 * EL;  // attn out [B,S,1024]
  // total 32M u16 = 64 MB of d_ws

  cvt_bf16<<<2048, 256, 0, stream>>>(q, QB);
  cvt_bf16<<<2048, 256, 0, stream>>>(k, KB);
  cvt_bf16<<<2048, 256, 0, stream>>>(v, VB);
  cvt_bf16<<<512, 256, 0, stream>>>(wq, WQ);
  cvt_bf16<<<512, 256, 0, stream>>>(wk, WK);
  cvt_bf16<<<512, 256, 0, stream>>>(wv, WV);
  cvt_bf16<<<512, 256, 0, stream>>>(wo, WO);

  gemm_qkv<<<dim3(8, 32, 3), 256, 0, stream>>>(QB, KB, VB, WQ, WK, WV, Qw, Kw, Vtw);
  attn_kernel<<<dim3(32, 32), 256, 0, stream>>>(Qw, Kw, Vtw, AO);
  gemm_out<<<dim3(8, 32), 256, 0, stream>>>(AO, WO, (float*)d_out);
}

// Round 2
// 232.881 us; speedup vs baseline: 1.5800x; 1.5800x over previous
//
#include <hip/hip_runtime.h>

typedef unsigned short u16;
typedef unsigned int   u32;
typedef __bf16 bf16x8 __attribute__((ext_vector_type(8)));
typedef float  f32x4  __attribute__((ext_vector_type(4)));
typedef unsigned short u16x4 __attribute__((ext_vector_type(4)));
typedef unsigned short u16x8 __attribute__((ext_vector_type(8)));
typedef unsigned int   u32x2 __attribute__((ext_vector_type(2)));
typedef unsigned int   u32x4 __attribute__((ext_vector_type(4)));

#define DIM   1024
#define SEQ   2048
#define NH    16
#define HD    64
#define NBATCH 2

#define NEG_INF (-__builtin_inff())

// ---------- helpers ----------

__device__ __forceinline__ u16 f2bf(float f) {
  unsigned u = __float_as_uint(f);
  unsigned r = (u + 0x7FFFu + ((u >> 16) & 1u)) >> 16;  // RNE
  return (u16)r;
}

// async global->LDS, 16B per lane. lds dest must be wave-uniform base (+lane*16 by HW).
__device__ __forceinline__ void gload16(const void* g, void* lds_uniform) {
  __builtin_amdgcn_global_load_lds(
      (__attribute__((address_space(1))) void*)(size_t)g,
      (__attribute__((address_space(3))) void*)lds_uniform,
      16, 0, 0);
}

// ---------- fused fp32 -> bf16 convert for all 7 tensors ----------
// ws layout (u16 elems, M = 1<<20): QB@0, KB@4M, VB@8M, WQ@12M, WK@13M, WV@14M, WO@15M

__global__ __launch_bounds__(256) void cvt_all(
    const float* __restrict__ q, const float* __restrict__ k, const float* __restrict__ v,
    const float* __restrict__ wq, const float* __restrict__ wk, const float* __restrict__ wv,
    const float* __restrict__ wo, u16* __restrict__ ws) {
  const size_t M = 1u << 20;
  int b = blockIdx.x;
  const float* src;
  u16* dst;
  int idx;
  if (b < 6144) {           // q,k,v: 2048 blocks each (4M elems)
    int t = b >> 11; idx = b & 2047;
    src = (t == 0) ? q : (t == 1) ? k : v;
    dst = ws + (size_t)t * 4 * M;
  } else {                  // weights: 512 blocks each (1M elems)
    int t = (b - 6144) >> 9; idx = (b - 6144) & 511;
    src = (t == 0) ? wq : (t == 1) ? wk : (t == 2) ? wv : wo;
    dst = ws + (12 + (size_t)t) * M;
  }
  size_t i = ((size_t)idx * 256 + threadIdx.x) * 8;
  float4 a = *(const float4*)(src + i);
  float4 c = *(const float4*)(src + i + 4);
  u16x8 o;
  o[0] = f2bf(a.x); o[1] = f2bf(a.y); o[2] = f2bf(a.z); o[3] = f2bf(a.w);
  o[4] = f2bf(c.x); o[5] = f2bf(c.y); o[6] = f2bf(c.z); o[7] = f2bf(c.w);
  *(u16x8*)(dst + i) = o;
}

// ---------- GEMM core: C[m,n] = sum_k A[m,k]*W[n,k], 128x128 tile, BK=32 ----------

__device__ __forceinline__ void gemm128_core(const u16* __restrict__ A,
                                             const u16* __restrict__ W,
                                             u16* lds, f32x4 (&acc)[4][4]) {
  const int K = 1024;
  const int tid = threadIdx.x;
  const int wave = tid >> 6, lane = tid & 63;
  const int quad = lane >> 4, l15 = lane & 15;
  const int warp_m = wave >> 1, warp_n = wave & 1;
  const int bm = blockIdx.y, bn = blockIdx.x;

  const int c0 = wave * 128 + lane, c1 = c0 + 64;
  const u16* Ag0 = A + (size_t)(bm * 128 + (c0 >> 2)) * K + (c0 & 3) * 8;
  const u16* Ag1 = A + (size_t)(bm * 128 + (c1 >> 2)) * K + (c1 & 3) * 8;
  const u16* Wg0 = W + (size_t)(bn * 128 + (c0 >> 2)) * K + (c0 & 3) * 8;
  const u16* Wg1 = W + (size_t)(bn * 128 + (c1 >> 2)) * K + (c1 & 3) * 8;
  u16* lA0 = lds + (wave * 2 + 0) * 512;
  u16* lA1 = lds + (wave * 2 + 1) * 512;
  u16* lB0 = lds + 4096 + (wave * 2 + 0) * 512;
  u16* lB1 = lds + 4096 + (wave * 2 + 1) * 512;

  for (int k0 = 0; k0 < K; k0 += 32) {
    gload16(Ag0 + k0, lA0);
    gload16(Ag1 + k0, lA1);
    gload16(Wg0 + k0, lB0);
    gload16(Wg1 + k0, lB1);
    __syncthreads();

    bf16x8 af[4], bfr[4];
#pragma unroll
    for (int i = 0; i < 4; ++i) {
      af[i]  = *(const bf16x8*)(lds + (warp_m * 64 + i * 16 + l15) * 32 + quad * 8);
      bfr[i] = *(const bf16x8*)(lds + 4096 + (warp_n * 64 + i * 16 + l15) * 32 + quad * 8);
    }
#pragma unroll
    for (int i = 0; i < 4; ++i)
#pragma unroll
      for (int j = 0; j < 4; ++j)
        acc[i][j] = __builtin_amdgcn_mfma_f32_16x16x32_bf16(af[i], bfr[j], acc[i][j], 0, 0, 0);
    __syncthreads();
  }
}

// QKV projection epilogues:
//   z=0 -> Q [bh][s][d], prescaled by 1/8
//   z=1 -> K [bh][s][d'] with d' chunk-swizzled by s&7  (conflict-free attn LDS reads)
//   z=2 -> V^T [bh][d][s'] with s' chunk-swizzled by d&7 within each 64-key group
__global__ __launch_bounds__(256) void gemm_qkv(
    const u16* __restrict__ qb, const u16* __restrict__ kb, const u16* __restrict__ vb,
    const u16* __restrict__ wq, const u16* __restrict__ wk, const u16* __restrict__ wv,
    u16* __restrict__ Qo, u16* __restrict__ Ko, u16* __restrict__ Vt) {
  __shared__ __align__(16) u16 lds[8192];
  const int z = blockIdx.z;
  const u16* A = (z == 0) ? qb : (z == 1) ? kb : vb;
  const u16* W = (z == 0) ? wq : (z == 1) ? wk : wv;
  f32x4 acc[4][4] = {};
  gemm128_core(A, W, lds, acc);

  const int tid = threadIdx.x;
  const int wave = tid >> 6, lane = tid & 63;
  const int quad = lane >> 4, l15 = lane & 15;
  const int warp_m = wave >> 1, warp_n = wave & 1;
  const int bm = blockIdx.y, bn = blockIdx.x;
#pragma unroll
  for (int i = 0; i < 4; ++i)
#pragma unroll
    for (int j = 0; j < 4; ++j) {
      int s0 = bm * 128 + warp_m * 64 + i * 16 + quad * 4;  // token base (r adds 0..3)
      int n  = bn * 128 + warp_n * 64 + j * 16 + l15;       // out dim
      int bb = s0 >> 11, sl0 = s0 & 2047, h = n >> 6, d = n & 63;
      if (z == 2) {
        // pack 4 consecutive tokens (r=0..3) into one 8B store, key-chunk swizzled by d&7
        int ssw = (sl0 & ~63) | ((((sl0 >> 3) & 7) ^ (d & 7)) << 3) | (sl0 & 7);
        u16x4 pv;
        pv[0] = f2bf(acc[i][j][0]); pv[1] = f2bf(acc[i][j][1]);
        pv[2] = f2bf(acc[i][j][2]); pv[3] = f2bf(acc[i][j][3]);
        *(u16x4*)(Vt + ((size_t)(bb * NH + h) * HD + d) * SEQ + ssw) = pv;
      } else if (z == 1) {
#pragma unroll
        for (int r = 0; r < 4; ++r) {
          int s = sl0 + r;
          int dsw = (((d >> 3) ^ (s & 7)) << 3) | (d & 7);
          Ko[((size_t)(bb * NH + h) * SEQ + s) * HD + dsw] = f2bf(acc[i][j][r]);
        }
      } else {
#pragma unroll
        for (int r = 0; r < 4; ++r)
          Qo[((size_t)(bb * NH + h) * SEQ + sl0 + r) * HD + d] = f2bf(acc[i][j][r] * 0.125f);
      }
    }
}

// output projection: fp32 out = AO @ wo^T
__global__ __launch_bounds__(256) void gemm_out(
    const u16* __restrict__ A, const u16* __restrict__ W, float* __restrict__ Out) {
  __shared__ __align__(16) u16 lds[8192];
  f32x4 acc[4][4] = {};
  gemm128_core(A, W, lds, acc);

  const int tid = threadIdx.x;
  const int wave = tid >> 6, lane = tid & 63;
  const int quad = lane >> 4, l15 = lane & 15;
  const int warp_m = wave >> 1, warp_n = wave & 1;
  const int bm = blockIdx.y, bn = blockIdx.x;
#pragma unroll
  for (int i = 0; i < 4; ++i)
#pragma unroll
    for (int j = 0; j < 4; ++j)
#pragma unroll
      for (int r = 0; r < 4; ++r) {
        int m = bm * 128 + warp_m * 64 + i * 16 + quad * 4 + r;
        int n = bn * 128 + warp_n * 64 + j * 16 + l15;
        Out[(size_t)m * DIM + n] = acc[i][j][r];
      }
}

// ---------- flash attention (causal), S^T formulation ----------
// Q: [bh][s][d] bf16 (prescaled); K: [bh][s][d-swizzled]; Vt: [bh][d][s-swizzled]
// block = 64 q-rows x one bh; wave w owns q rows qt*64 + w*16 + l15 (q on l15)

__global__ __launch_bounds__(256) void attn_kernel(
    const u16* __restrict__ Q, const u16* __restrict__ K,
    const u16* __restrict__ Vt, u16* __restrict__ O) {
  __shared__ __align__(16) u16 Kl[2][4096];   // [key][d'] swizzled, double-buffered
  __shared__ __align__(16) u16 Vl[2][4096];   // [d][key'] swizzled, double-buffered
  __shared__ __align__(16) u32 Plm[4][16 * 36]; // per-wave P: [q][key], 36-dword rows (pad)

  const int tid = threadIdx.x;
  const int wave = tid >> 6, lane = tid & 63;
  const int quad = lane >> 4, l15 = lane & 15;
  const int bx = blockIdx.x;
  const int bh = bx & 31;
  const int qt = 31 - (bx >> 5);              // reversed: longest blocks first
  const int b = bh >> 4, h = bh & 15;

  // Q as B-operand: B[n=l15][k=quad*8+j], prescaled by 1/8 already
  const u16* qbase = Q + ((size_t)bh * SEQ + qt * 64 + wave * 16 + l15) * HD + quad * 8;
  const bf16x8 qf0 = *(const bf16x8*)(qbase);
  const bf16x8 qf1 = *(const bf16x8*)(qbase + 32);

  f32x4 o[4] = {};
  float l_sum = 0.f, m_run = NEG_INF;         // per-lane: q = l15 (dup across quads)

  const int c0 = wave * 128 + lane, c1 = c0 + 64;  // staging chunk ids (16B each)
  const u16* Ksrc = K + (size_t)bh * SEQ * HD;
  const u16* Vsrc = Vt + (size_t)bh * HD * SEQ;
  const int sw0 = ((quad ^ (l15 & 7)) << 3);       // swizzled chunk offsets for frag reads
  const int sw1 = (((4 + quad) ^ (l15 & 7)) << 3);

  // initial stage of tile 0 into buffer 0
  {
    gload16(Ksrc + (size_t)c0 * 8, &Kl[0][(wave * 2 + 0) * 512]);
    gload16(Ksrc + (size_t)c1 * 8, &Kl[0][(wave * 2 + 1) * 512]);
    gload16(Vsrc + (size_t)(c0 >> 3) * SEQ + (c0 & 7) * 8, &Vl[0][(wave * 2 + 0) * 512]);
    gload16(Vsrc + (size_t)(c1 >> 3) * SEQ + (c1 & 7) * 8, &Vl[0][(wave * 2 + 1) * 512]);
  }

  u32* prow = &Plm[wave][l15 * 36];

  for (int kt = 0; kt <= qt; ++kt) {
    const int buf = kt & 1;
    __syncthreads();   // drains stage(kt); all waves done reading buf from kt-1
    if (kt < qt) {     // prefetch tile kt+1 into the other buffer (flies during compute)
      const int nb = buf ^ 1;
      const size_t kb = (size_t)(kt + 1) * 64;
      gload16(Ksrc + (kb * HD) + (size_t)c0 * 8, &Kl[nb][(wave * 2 + 0) * 512]);
      gload16(Ksrc + (kb * HD) + (size_t)c1 * 8, &Kl[nb][(wave * 2 + 1) * 512]);
      gload16(Vsrc + (size_t)(c0 >> 3) * SEQ + kb + (c0 & 7) * 8, &Vl[nb][(wave * 2 + 0) * 512]);
      gload16(Vsrc + (size_t)(c1 >> 3) * SEQ + kb + (c1 & 7) * 8, &Vl[nb][(wave * 2 + 1) * 512]);
    }

    // S^T = K Q^T : C[row=key local (kn*16 + quad*4 + r)][col=q=l15]
    f32x4 s[4];
#pragma unroll
    for (int kn = 0; kn < 4; ++kn) {
      const u16* arow = &Kl[buf][(kn * 16 + l15) * 64];
      bf16x8 kf0 = *(const bf16x8*)(arow + sw0);
      bf16x8 kf1 = *(const bf16x8*)(arow + sw1);
      f32x4 z = {};
      z = __builtin_amdgcn_mfma_f32_16x16x32_bf16(kf0, qf0, z, 0, 0, 0);
      z = __builtin_amdgcn_mfma_f32_16x16x32_bf16(kf1, qf1, z, 0, 0, 0);
      s[kn] = z;
    }

    if (kt == qt) {  // diagonal tile: mask key > q
      const int qloc = wave * 16 + l15;
#pragma unroll
      for (int kn = 0; kn < 4; ++kn)
#pragma unroll
        for (int r = 0; r < 4; ++r)
          if (kn * 16 + quad * 4 + r > qloc) s[kn][r] = NEG_INF;
    }

    // online softmax: 16 in-lane values + 2 cross-quad shuffles per reduction
    float mr = NEG_INF;
#pragma unroll
    for (int kn = 0; kn < 4; ++kn)
#pragma unroll
      for (int r = 0; r < 4; ++r) mr = fmaxf(mr, s[kn][r]);
    mr = fmaxf(mr, __shfl_xor(mr, 16));
    mr = fmaxf(mr, __shfl_xor(mr, 32));
    const float mnew = fmaxf(m_run, mr);
    const float alpha = __expf(m_run - mnew);
    m_run = mnew;
    float rs = 0.f;
#pragma unroll
    for (int kn = 0; kn < 4; ++kn)
#pragma unroll
      for (int r = 0; r < 4; ++r) {
        float p = __expf(s[kn][r] - mnew);
        s[kn][r] = p;
        rs += p;
      }
    rs += __shfl_xor(rs, 16);
    rs += __shfl_xor(rs, 32);
    l_sum = l_sum * alpha + rs;

    // rescale O: O rows are q = quad*4 + r -> fetch alpha from lane quad*4+r
    float aT[4];
#pragma unroll
    for (int r = 0; r < 4; ++r) aT[r] = __shfl(alpha, quad * 4 + r);
#pragma unroll
    for (int n = 0; n < 4; ++n)
#pragma unroll
      for (int r = 0; r < 4; ++r) o[n][r] *= aT[r];

    // P (bf16) -> per-wave LDS [q=l15][key], then reload as A-operand fragments
#pragma unroll
    for (int kn = 0; kn < 4; ++kn) {
      u32x2 w;
      w[0] = (u32)f2bf(s[kn][0]) | ((u32)f2bf(s[kn][1]) << 16);
      w[1] = (u32)f2bf(s[kn][2]) | ((u32)f2bf(s[kn][3]) << 16);
      *(u32x2*)(prow + kn * 8 + quad * 2) = w;
    }
    u32x4 t0 = *(const u32x4*)(prow + quad * 4);
    u32x4 t1 = *(const u32x4*)(prow + 16 + quad * 4);
    bf16x8 pf0 = __builtin_bit_cast(bf16x8, t0);
    bf16x8 pf1 = __builtin_bit_cast(bf16x8, t1);

    // O += P V : A = P (m=q), B = V^T (n=d), C[row=q quad*4+r][col=d l15]
#pragma unroll
    for (int n = 0; n < 4; ++n) {
      const u16* vrow = &Vl[buf][(n * 16 + l15) * 64];
      bf16x8 vf0 = *(const bf16x8*)(vrow + sw0);
      bf16x8 vf1 = *(const bf16x8*)(vrow + sw1);
      o[n] = __builtin_amdgcn_mfma_f32_16x16x32_bf16(pf0, vf0, o[n], 0, 0, 0);
      o[n] = __builtin_amdgcn_mfma_f32_16x16x32_bf16(pf1, vf1, o[n], 0, 0, 0);
    }
  }

  // epilogue: O /= l (l for q=quad*4+r lives in lane quad*4+r), write AO [b][s][h*64+d]
  float inv = 1.f / l_sum;
  float iT[4];
#pragma unroll
  for (int r = 0; r < 4; ++r) iT[r] = __shfl(inv, quad * 4 + r);
#pragma unroll
  for (int r = 0; r < 4; ++r) {
    int srow = qt * 64 + wave * 16 + quad * 4 + r;
#pragma unroll
    for (int n = 0; n < 4; ++n) {
      int col = h * HD + n * 16 + l15;
      O[((size_t)b * SEQ + srow) * DIM + col] = f2bf(o[n][r] * iT[r]);
    }
  }
}

// ---------- launch ----------

extern "C" void kernel_launch(void* const* d_in, const int* in_sizes, int n_in,
                              void* d_out, int out_size, void* d_ws, size_t ws_size,
                              hipStream_t stream) {
  (void)in_sizes; (void)n_in; (void)out_size; (void)ws_size;
  const float* q  = (const float*)d_in[0];
  const float* k  = (const float*)d_in[1];
  const float* v  = (const float*)d_in[2];
  const float* wq = (const float*)d_in[3];
  const float* wk = (const float*)d_in[4];
  const float* wv = (const float*)d_in[5];
  const float* wv2 = (const float*)d_in[5];
  const float* wo = (const float*)d_in[6];
  (void)wv2;

  u16* ws = (u16*)d_ws;
  const size_t EL = 1u << 20;
  u16* QB = ws + 0 * EL;
  u16* KB = ws + 4 * EL;
  u16* VB = ws + 8 * EL;
  u16* WQ = ws + 12 * EL;
  u16* WK = ws + 13 * EL;
  u16* WV = ws + 14 * EL;
  u16* WO = ws + 15 * EL;
  u16* Qw = ws + 16 * EL;   // Q  [bh][s][64] prescaled
  u16* Kw = ws + 20 * EL;   // K  [bh][s][64] swizzled
  u16* Vtw = ws + 24 * EL;  // V^T [bh][64][s] swizzled
  u16* AO = ws + 28 * EL;   // attn out [b][s][1024]

  cvt_all<<<8192, 256, 0, stream>>>(q, k, v, wq, wk, wv, wo, ws);
  gemm_qkv<<<dim3(8, 32, 3), 256, 0, stream>>>(QB, KB, VB, WQ, WK, WV, Qw, Kw, Vtw);
  attn_kernel<<<1024, 256, 0, stream>>>(Qw, Kw, Vtw, AO);
  gemm_out<<<dim3(8, 32), 256, 0, stream>>>(AO, WO, (float*)d_out);
}

// Round 3
// 203.154 us; speedup vs baseline: 1.8112x; 1.1463x over previous
//
#include <hip/hip_runtime.h>

typedef unsigned short u16;
typedef unsigned int   u32;
typedef __bf16 bf16x8 __attribute__((ext_vector_type(8)));
typedef float  f32x4  __attribute__((ext_vector_type(4)));
typedef unsigned short u16x4 __attribute__((ext_vector_type(4)));
typedef unsigned short u16x8 __attribute__((ext_vector_type(8)));
typedef unsigned int   u32x2 __attribute__((ext_vector_type(2)));
typedef unsigned int   u32x4 __attribute__((ext_vector_type(4)));

#define DIM   1024
#define SEQ   2048
#define NH    16
#define HD    64
#define NBATCH 2

#define NEG_INF (-__builtin_inff())

// ---------- helpers ----------

__device__ __forceinline__ u16 f2bf(float f) {
  unsigned u = __float_as_uint(f);
  unsigned r = (u + 0x7FFFu + ((u >> 16) & 1u)) >> 16;  // RNE
  return (u16)r;
}

// async global->LDS, 16B per lane. lds dest must be wave-uniform base (+lane*16 by HW).
__device__ __forceinline__ void gload16(const void* g, void* lds_uniform) {
  __builtin_amdgcn_global_load_lds(
      (__attribute__((address_space(1))) void*)(size_t)g,
      (__attribute__((address_space(3))) void*)lds_uniform,
      16, 0, 0);
}

// ---------- fused fp32 -> bf16 convert for all 7 tensors ----------
// ws layout (u16 elems, M = 1<<20): QB@0, KB@4M, VB@8M, WQ@12M, WK@13M, WV@14M, WO@15M

__global__ __launch_bounds__(256) void cvt_all(
    const float* __restrict__ q, const float* __restrict__ k, const float* __restrict__ v,
    const float* __restrict__ wq, const float* __restrict__ wk, const float* __restrict__ wv,
    const float* __restrict__ wo, u16* __restrict__ ws) {
  const size_t M = 1u << 20;
  int b = blockIdx.x;
  const float* src;
  u16* dst;
  int idx;
  if (b < 6144) {           // q,k,v: 2048 blocks each (4M elems)
    int t = b >> 11; idx = b & 2047;
    src = (t == 0) ? q : (t == 1) ? k : v;
    dst = ws + (size_t)t * 4 * M;
  } else {                  // weights: 512 blocks each (1M elems)
    int t = (b - 6144) >> 9; idx = (b - 6144) & 511;
    src = (t == 0) ? wq : (t == 1) ? wk : (t == 2) ? wv : wo;
    dst = ws + (12 + (size_t)t) * M;
  }
  size_t i = ((size_t)idx * 256 + threadIdx.x) * 8;
  float4 a = *(const float4*)(src + i);
  float4 c = *(const float4*)(src + i + 4);
  u16x8 o;
  o[0] = f2bf(a.x); o[1] = f2bf(a.y); o[2] = f2bf(a.z); o[3] = f2bf(a.w);
  o[4] = f2bf(c.x); o[5] = f2bf(c.y); o[6] = f2bf(c.z); o[7] = f2bf(c.w);
  *(u16x8*)(dst + i) = o;
}

// ---------- GEMM core: C[m,n] = sum_k A[m,k]*W[n,k], 128x128 tile, BK=32 ----------
// Double-buffered LDS, ONE barrier per K-iter, prefetch issued right after the
// barrier so global_load_lds flies during the 16 MFMAs (drain ~free at next barrier).
// lds layout: [2][8192]: buf b -> A-tile at b*8192, W-tile at b*8192+4096.

__device__ __forceinline__ void gemm128_core(const u16* __restrict__ A,
                                             const u16* __restrict__ W,
                                             int bm, int bn,
                                             u16* lds, f32x4 (&acc)[4][4]) {
  const int K = 1024;
  const int tid = threadIdx.x;
  const int wave = tid >> 6, lane = tid & 63;
  const int quad = lane >> 4, l15 = lane & 15;
  const int warp_m = wave >> 1, warp_n = wave & 1;

  const int c0 = wave * 128 + lane, c1 = c0 + 64;  // 16B chunk ids within tile
  const u16* Ag0 = A + (size_t)(bm * 128 + (c0 >> 2)) * K + (c0 & 3) * 8;
  const u16* Ag1 = A + (size_t)(bm * 128 + (c1 >> 2)) * K + (c1 & 3) * 8;
  const u16* Wg0 = W + (size_t)(bn * 128 + (c0 >> 2)) * K + (c0 & 3) * 8;
  const u16* Wg1 = W + (size_t)(bn * 128 + (c1 >> 2)) * K + (c1 & 3) * 8;
  const int lA0 = (wave * 2 + 0) * 512;
  const int lA1 = (wave * 2 + 1) * 512;
  const int lB0 = 4096 + (wave * 2 + 0) * 512;
  const int lB1 = 4096 + (wave * 2 + 1) * 512;

  // prologue: stage tile 0 into buffer 0
  gload16(Ag0, lds + lA0);
  gload16(Ag1, lds + lA1);
  gload16(Wg0, lds + lB0);
  gload16(Wg1, lds + lB1);

  for (int k0 = 0; k0 < K; k0 += 32) {
    const int buf = (k0 >> 5) & 1;
    u16* cur = lds + buf * 8192;
    __syncthreads();             // drains the prefetch of THIS tile (in flight
                                 // since last iter) + protects buf^1 for reuse
    if (k0 + 32 < K) {           // prefetch next tile into the other buffer
      u16* nxt = lds + (buf ^ 1) * 8192;
      gload16(Ag0 + k0 + 32, nxt + lA0);
      gload16(Ag1 + k0 + 32, nxt + lA1);
      gload16(Wg0 + k0 + 32, nxt + lB0);
      gload16(Wg1 + k0 + 32, nxt + lB1);
    }

    bf16x8 af[4], bfr[4];
#pragma unroll
    for (int i = 0; i < 4; ++i) {
      af[i]  = *(const bf16x8*)(cur + (warp_m * 64 + i * 16 + l15) * 32 + quad * 8);
      bfr[i] = *(const bf16x8*)(cur + 4096 + (warp_n * 64 + i * 16 + l15) * 32 + quad * 8);
    }
#pragma unroll
    for (int i = 0; i < 4; ++i)
#pragma unroll
      for (int j = 0; j < 4; ++j)
        acc[i][j] = __builtin_amdgcn_mfma_f32_16x16x32_bf16(af[i], bfr[j], acc[i][j], 0, 0, 0);
  }
}

// QKV projection. 1-D grid of 768, XCD-aware decode: xcd = id&7; all 8 bn of a
// (bm,z) group share one XCD -> A-stripe + W stay in that XCD's 4MB L2.
//   z=0 -> Q [bh][s][d], prescaled by 1/8
//   z=1 -> K [bh][s][d'] with d' chunk-swizzled by s&7  (conflict-free attn LDS reads)
//   z=2 -> V^T [bh][d][s'] with s' chunk-swizzled by d&7 within each 64-key group
__global__ __launch_bounds__(256) void gemm_qkv(
    const u16* __restrict__ qb, const u16* __restrict__ kb, const u16* __restrict__ vb,
    const u16* __restrict__ wq, const u16* __restrict__ wk, const u16* __restrict__ wv,
    u16* __restrict__ Qo, u16* __restrict__ Ko, u16* __restrict__ Vt) {
  __shared__ __align__(16) u16 lds[2][8192];
  const int id = blockIdx.x;
  const int c = id & 7, bn = (id >> 3) & 7, t = id >> 6;  // t in 0..11
  const int g = c + 8 * t;                                // 0..95
  const int bm = g & 31, z = g >> 5;

  const u16* A = (z == 0) ? qb : (z == 1) ? kb : vb;
  const u16* W = (z == 0) ? wq : (z == 1) ? wk : wv;
  f32x4 acc[4][4] = {};
  gemm128_core(A, W, bm, bn, &lds[0][0], acc);

  const int tid = threadIdx.x;
  const int wave = tid >> 6, lane = tid & 63;
  const int quad = lane >> 4, l15 = lane & 15;
  const int warp_m = wave >> 1, warp_n = wave & 1;
#pragma unroll
  for (int i = 0; i < 4; ++i)
#pragma unroll
    for (int j = 0; j < 4; ++j) {
      int s0 = bm * 128 + warp_m * 64 + i * 16 + quad * 4;  // token base (r adds 0..3)
      int n  = bn * 128 + warp_n * 64 + j * 16 + l15;       // out dim
      int bb = s0 >> 11, sl0 = s0 & 2047, h = n >> 6, d = n & 63;
      if (z == 2) {
        // pack 4 consecutive tokens (r=0..3) into one 8B store, key-chunk swizzled by d&7
        int ssw = (sl0 & ~63) | ((((sl0 >> 3) & 7) ^ (d & 7)) << 3) | (sl0 & 7);
        u16x4 pv;
        pv[0] = f2bf(acc[i][j][0]); pv[1] = f2bf(acc[i][j][1]);
        pv[2] = f2bf(acc[i][j][2]); pv[3] = f2bf(acc[i][j][3]);
        *(u16x4*)(Vt + ((size_t)(bb * NH + h) * HD + d) * SEQ + ssw) = pv;
      } else if (z == 1) {
#pragma unroll
        for (int r = 0; r < 4; ++r) {
          int s = sl0 + r;
          int dsw = (((d >> 3) ^ (s & 7)) << 3) | (d & 7);
          Ko[((size_t)(bb * NH + h) * SEQ + s) * HD + dsw] = f2bf(acc[i][j][r]);
        }
      } else {
#pragma unroll
        for (int r = 0; r < 4; ++r)
          Qo[((size_t)(bb * NH + h) * SEQ + sl0 + r) * HD + d] = f2bf(acc[i][j][r] * 0.125f);
      }
    }
}

// output projection: fp32 out = AO @ wo^T. 1-D grid of 256, XCD-aware decode.
__global__ __launch_bounds__(256) void gemm_out(
    const u16* __restrict__ A, const u16* __restrict__ W, float* __restrict__ Out) {
  __shared__ __align__(16) u16 lds[2][8192];
  const int id = blockIdx.x;
  const int bn = (id >> 3) & 7;
  const int bm = (id & 7) + 8 * (id >> 6);
  f32x4 acc[4][4] = {};
  gemm128_core(A, W, bm, bn, &lds[0][0], acc);

  const int tid = threadIdx.x;
  const int wave = tid >> 6, lane = tid & 63;
  const int quad = lane >> 4, l15 = lane & 15;
  const int warp_m = wave >> 1, warp_n = wave & 1;
#pragma unroll
  for (int i = 0; i < 4; ++i)
#pragma unroll
    for (int j = 0; j < 4; ++j)
#pragma unroll
      for (int r = 0; r < 4; ++r) {
        int m = bm * 128 + warp_m * 64 + i * 16 + quad * 4 + r;
        int n = bn * 128 + warp_n * 64 + j * 16 + l15;
        Out[(size_t)m * DIM + n] = acc[i][j][r];
      }
}

// ---------- flash attention (causal), S^T formulation ----------
// Q: [bh][s][d] bf16 (prescaled); K: [bh][s][d-swizzled]; Vt: [bh][d][s-swizzled]
// block = 64 q-rows x one bh; wave w owns q rows qt*64 + w*16 + l15 (q on l15)

__global__ __launch_bounds__(256) void attn_kernel(
    const u16* __restrict__ Q, const u16* __restrict__ K,
    const u16* __restrict__ Vt, u16* __restrict__ O) {
  __shared__ __align__(16) u16 Kl[2][4096];   // [key][d'] swizzled, double-buffered
  __shared__ __align__(16) u16 Vl[2][4096];   // [d][key'] swizzled, double-buffered
  __shared__ __align__(16) u32 Plm[4][16 * 36]; // per-wave P: [q][key], 36-dword rows (pad)

  const int tid = threadIdx.x;
  const int wave = tid >> 6, lane = tid & 63;
  const int quad = lane >> 4, l15 = lane & 15;
  const int bx = blockIdx.x;
  const int bh = bx & 31;
  const int qt = 31 - (bx >> 5);              // reversed: longest blocks first
  const int b = bh >> 4, h = bh & 15;

  // Q as B-operand: B[n=l15][k=quad*8+j], prescaled by 1/8 already
  const u16* qbase = Q + ((size_t)bh * SEQ + qt * 64 + wave * 16 + l15) * HD + quad * 8;
  const bf16x8 qf0 = *(const bf16x8*)(qbase);
  const bf16x8 qf1 = *(const bf16x8*)(qbase + 32);

  f32x4 o[4] = {};
  float l_sum = 0.f, m_run = NEG_INF;         // per-lane: q = l15 (dup across quads)

  const int c0 = wave * 128 + lane, c1 = c0 + 64;  // staging chunk ids (16B each)
  const u16* Ksrc = K + (size_t)bh * SEQ * HD;
  const u16* Vsrc = Vt + (size_t)bh * HD * SEQ;
  const int sw0 = ((quad ^ (l15 & 7)) << 3);       // swizzled chunk offsets for frag reads
  const int sw1 = (((4 + quad) ^ (l15 & 7)) << 3);

  // initial stage of tile 0 into buffer 0
  {
    gload16(Ksrc + (size_t)c0 * 8, &Kl[0][(wave * 2 + 0) * 512]);
    gload16(Ksrc + (size_t)c1 * 8, &Kl[0][(wave * 2 + 1) * 512]);
    gload16(Vsrc + (size_t)(c0 >> 3) * SEQ + (c0 & 7) * 8, &Vl[0][(wave * 2 + 0) * 512]);
    gload16(Vsrc + (size_t)(c1 >> 3) * SEQ + (c1 & 7) * 8, &Vl[0][(wave * 2 + 1) * 512]);
  }

  u32* prow = &Plm[wave][l15 * 36];

  for (int kt = 0; kt <= qt; ++kt) {
    const int buf = kt & 1;
    __syncthreads();   // drains stage(kt); all waves done reading buf from kt-1
    if (kt < qt) {     // prefetch tile kt+1 into the other buffer (flies during compute)
      const int nb = buf ^ 1;
      const size_t kb = (size_t)(kt + 1) * 64;
      gload16(Ksrc + (kb * HD) + (size_t)c0 * 8, &Kl[nb][(wave * 2 + 0) * 512]);
      gload16(Ksrc + (kb * HD) + (size_t)c1 * 8, &Kl[nb][(wave * 2 + 1) * 512]);
      gload16(Vsrc + (size_t)(c0 >> 3) * SEQ + kb + (c0 & 7) * 8, &Vl[nb][(wave * 2 + 0) * 512]);
      gload16(Vsrc + (size_t)(c1 >> 3) * SEQ + kb + (c1 & 7) * 8, &Vl[nb][(wave * 2 + 1) * 512]);
    }

    // S^T = K Q^T : C[row=key local (kn*16 + quad*4 + r)][col=q=l15]
    f32x4 s[4];
#pragma unroll
    for (int kn = 0; kn < 4; ++kn) {
      const u16* arow = &Kl[buf][(kn * 16 + l15) * 64];
      bf16x8 kf0 = *(const bf16x8*)(arow + sw0);
      bf16x8 kf1 = *(const bf16x8*)(arow + sw1);
      f32x4 z = {};
      z = __builtin_amdgcn_mfma_f32_16x16x32_bf16(kf0, qf0, z, 0, 0, 0);
      z = __builtin_amdgcn_mfma_f32_16x16x32_bf16(kf1, qf1, z, 0, 0, 0);
      s[kn] = z;
    }

    if (kt == qt) {  // diagonal tile: mask key > q
      const int qloc = wave * 16 + l15;
#pragma unroll
      for (int kn = 0; kn < 4; ++kn)
#pragma unroll
        for (int r = 0; r < 4; ++r)
          if (kn * 16 + quad * 4 + r > qloc) s[kn][r] = NEG_INF;
    }

    // online softmax: 16 in-lane values + 2 cross-quad shuffles per reduction
    float mr = NEG_INF;
#pragma unroll
    for (int kn = 0; kn < 4; ++kn)
#pragma unroll
      for (int r = 0; r < 4; ++r) mr = fmaxf(mr, s[kn][r]);
    mr = fmaxf(mr, __shfl_xor(mr, 16));
    mr = fmaxf(mr, __shfl_xor(mr, 32));
    const float mnew = fmaxf(m_run, mr);
    const float alpha = __expf(m_run - mnew);
    m_run = mnew;
    float rs = 0.f;
#pragma unroll
    for (int kn = 0; kn < 4; ++kn)
#pragma unroll
      for (int r = 0; r < 4; ++r) {
        float p = __expf(s[kn][r] - mnew);
        s[kn][r] = p;
        rs += p;
      }
    rs += __shfl_xor(rs, 16);
    rs += __shfl_xor(rs, 32);
    l_sum = l_sum * alpha + rs;

    // rescale O: O rows are q = quad*4 + r -> fetch alpha from lane quad*4+r
    float aT[4];
#pragma unroll
    for (int r = 0; r < 4; ++r) aT[r] = __shfl(alpha, quad * 4 + r);
#pragma unroll
    for (int n = 0; n < 4; ++n)
#pragma unroll
      for (int r = 0; r < 4; ++r) o[n][r] *= aT[r];

    // P (bf16) -> per-wave LDS [q=l15][key], then reload as A-operand fragments
#pragma unroll
    for (int kn = 0; kn < 4; ++kn) {
      u32x2 w;
      w[0] = (u32)f2bf(s[kn][0]) | ((u32)f2bf(s[kn][1]) << 16);
      w[1] = (u32)f2bf(s[kn][2]) | ((u32)f2bf(s[kn][3]) << 16);
      *(u32x2*)(prow + kn * 8 + quad * 2) = w;
    }
    u32x4 t0 = *(const u32x4*)(prow + quad * 4);
    u32x4 t1 = *(const u32x4*)(prow + 16 + quad * 4);
    bf16x8 pf0 = __builtin_bit_cast(bf16x8, t0);
    bf16x8 pf1 = __builtin_bit_cast(bf16x8, t1);

    // O += P V : A = P (m=q), B = V^T (n=d), C[row=q quad*4+r][col=d l15]
#pragma unroll
    for (int n = 0; n < 4; ++n) {
      const u16* vrow = &Vl[buf][(n * 16 + l15) * 64];
      bf16x8 vf0 = *(const bf16x8*)(vrow + sw0);
      bf16x8 vf1 = *(const bf16x8*)(vrow + sw1);
      o[n] = __builtin_amdgcn_mfma_f32_16x16x32_bf16(pf0, vf0, o[n], 0, 0, 0);
      o[n] = __builtin_amdgcn_mfma_f32_16x16x32_bf16(pf1, vf1, o[n], 0, 0, 0);
    }
  }

  // epilogue: O /= l (l for q=quad*4+r lives in lane quad*4+r), write AO [b][s][h*64+d]
  float inv = 1.f / l_sum;
  float iT[4];
#pragma unroll
  for (int r = 0; r < 4; ++r) iT[r] = __shfl(inv, quad * 4 + r);
#pragma unroll
  for (int r = 0; r < 4; ++r) {
    int srow = qt * 64 + wave * 16 + quad * 4 + r;
#pragma unroll
    for (int n = 0; n < 4; ++n) {
      int col = h * HD + n * 16 + l15;
      O[((size_t)b * SEQ + srow) * DIM + col] = f2bf(o[n][r] * iT[r]);
    }
  }
}

// ---------- launch ----------

extern "C" void kernel_launch(void* const* d_in, const int* in_sizes, int n_in,
                              void* d_out, int out_size, void* d_ws, size_t ws_size,
                              hipStream_t stream) {
  (void)in_sizes; (void)n_in; (void)out_size; (void)ws_size;
  const float* q  = (const float*)d_in[0];
  const float* k  = (const float*)d_in[1];
  const float* v  = (const float*)d_in[2];
  const float* wq = (const float*)d_in[3];
  const float* wk = (const float*)d_in[4];
  const float* wv = (const float*)d_in[5];
  const float* wo = (const float*)d_in[6];

  u16* ws = (u16*)d_ws;
  const size_t EL = 1u << 20;
  u16* QB = ws + 0 * EL;
  u16* KB = ws + 4 * EL;
  u16* VB = ws + 8 * EL;
  u16* WQ = ws + 12 * EL;
  u16* WK = ws + 13 * EL;
  u16* WV = ws + 14 * EL;
  u16* WO = ws + 15 * EL;
  u16* Qw = ws + 16 * EL;   // Q  [bh][s][64] prescaled
  u16* Kw = ws + 20 * EL;   // K  [bh][s][64] swizzled
  u16* Vtw = ws + 24 * EL;  // V^T [bh][64][s] swizzled
  u16* AO = ws + 28 * EL;   // attn out [b][s][1024]

  cvt_all<<<8192, 256, 0, stream>>>(q, k, v, wq, wk, wv, wo, ws);
  gemm_qkv<<<768, 256, 0, stream>>>(QB, KB, VB, WQ, WK, WV, Qw, Kw, Vtw);
  attn_kernel<<<1024, 256, 0, stream>>>(Qw, Kw, Vtw, AO);
  gemm_out<<<256, 256, 0, stream>>>(AO, WO, (float*)d_out);
}

// Round 4
// 202.426 us; speedup vs baseline: 1.8177x; 1.0036x over previous
//
#include <hip/hip_runtime.h>

typedef unsigned short u16;
typedef unsigned int   u32;
typedef __bf16 bf16x8 __attribute__((ext_vector_type(8)));
typedef float  f32x4  __attribute__((ext_vector_type(4)));
typedef unsigned short u16x4 __attribute__((ext_vector_type(4)));
typedef unsigned short u16x8 __attribute__((ext_vector_type(8)));
typedef unsigned int   u32x2 __attribute__((ext_vector_type(2)));
typedef unsigned int   u32x4 __attribute__((ext_vector_type(4)));

#define DIM   1024
#define SEQ   2048
#define NH    16
#define HD    64
#define NBATCH 2

#define NEG_INF (-__builtin_inff())
// 0.125 * log2(e): Q pre-scale so attention works in exp2 domain
#define QSCALE 0.1803368801111204f

// ---------- helpers ----------

__device__ __forceinline__ u16 f2bf(float f) {
  unsigned u = __float_as_uint(f);
  unsigned r = (u + 0x7FFFu + ((u >> 16) & 1u)) >> 16;  // RNE
  return (u16)r;
}

// pack two f32 -> two bf16 in one dword (v_cvt_pk_bf16_f32 on gfx950)
__device__ __forceinline__ u32 pkbf(float a, float b) {
#if __has_builtin(__builtin_amdgcn_cvt_pk_bf16_f32)
  typedef __bf16 bf16x2 __attribute__((ext_vector_type(2)));
  bf16x2 t = __builtin_amdgcn_cvt_pk_bf16_f32(a, b);
  return __builtin_bit_cast(u32, t);
#else
  return (u32)f2bf(a) | ((u32)f2bf(b) << 16);
#endif
}

// async global->LDS, 16B per lane. lds dest must be wave-uniform base (+lane*16 by HW).
__device__ __forceinline__ void gload16(const void* g, void* lds_uniform) {
  __builtin_amdgcn_global_load_lds(
      (__attribute__((address_space(1))) void*)(size_t)g,
      (__attribute__((address_space(3))) void*)lds_uniform,
      16, 0, 0);
}

// ---------- fused fp32 -> bf16 convert for all 7 tensors ----------
// ws layout (u16 elems, M = 1<<20): QB@0, KB@4M, VB@8M, WQ@12M, WK@13M, WV@14M, WO@15M

__global__ __launch_bounds__(256) void cvt_all(
    const float* __restrict__ q, const float* __restrict__ k, const float* __restrict__ v,
    const float* __restrict__ wq, const float* __restrict__ wk, const float* __restrict__ wv,
    const float* __restrict__ wo, u16* __restrict__ ws) {
  const size_t M = 1u << 20;
  int b = blockIdx.x;
  const float* src;
  u16* dst;
  int idx;
  if (b < 6144) {           // q,k,v: 2048 blocks each (4M elems)
    int t = b >> 11; idx = b & 2047;
    src = (t == 0) ? q : (t == 1) ? k : v;
    dst = ws + (size_t)t * 4 * M;
  } else {                  // weights: 512 blocks each (1M elems)
    int t = (b - 6144) >> 9; idx = (b - 6144) & 511;
    src = (t == 0) ? wq : (t == 1) ? wk : (t == 2) ? wv : wo;
    dst = ws + (12 + (size_t)t) * M;
  }
  size_t i = ((size_t)idx * 256 + threadIdx.x) * 8;
  float4 a = *(const float4*)(src + i);
  float4 c = *(const float4*)(src + i + 4);
  u16x8 o;
  o[0] = f2bf(a.x); o[1] = f2bf(a.y); o[2] = f2bf(a.z); o[3] = f2bf(a.w);
  o[4] = f2bf(c.x); o[5] = f2bf(c.y); o[6] = f2bf(c.z); o[7] = f2bf(c.w);
  *(u16x8*)(dst + i) = o;
}

// ---------- GEMM core: C[m,n] = sum_k A[m,k]*W[n,k], 128x128 tile, BK=32 ----------
// Double-buffered LDS, ONE barrier per K-iter, prefetch issued right after the
// barrier so global_load_lds flies during the 16 MFMAs.

__device__ __forceinline__ void gemm128_core(const u16* __restrict__ A,
                                             const u16* __restrict__ W,
                                             int bm, int bn,
                                             u16* lds, f32x4 (&acc)[4][4]) {
  const int K = 1024;
  const int tid = threadIdx.x;
  const int wave = tid >> 6, lane = tid & 63;
  const int quad = lane >> 4, l15 = lane & 15;
  const int warp_m = wave >> 1, warp_n = wave & 1;

  const int c0 = wave * 128 + lane, c1 = c0 + 64;  // 16B chunk ids within tile
  const u16* Ag0 = A + (size_t)(bm * 128 + (c0 >> 2)) * K + (c0 & 3) * 8;
  const u16* Ag1 = A + (size_t)(bm * 128 + (c1 >> 2)) * K + (c1 & 3) * 8;
  const u16* Wg0 = W + (size_t)(bn * 128 + (c0 >> 2)) * K + (c0 & 3) * 8;
  const u16* Wg1 = W + (size_t)(bn * 128 + (c1 >> 2)) * K + (c1 & 3) * 8;
  const int lA0 = (wave * 2 + 0) * 512;
  const int lA1 = (wave * 2 + 1) * 512;
  const int lB0 = 4096 + (wave * 2 + 0) * 512;
  const int lB1 = 4096 + (wave * 2 + 1) * 512;

  // prologue: stage tile 0 into buffer 0
  gload16(Ag0, lds + lA0);
  gload16(Ag1, lds + lA1);
  gload16(Wg0, lds + lB0);
  gload16(Wg1, lds + lB1);

  for (int k0 = 0; k0 < K; k0 += 32) {
    const int buf = (k0 >> 5) & 1;
    u16* cur = lds + buf * 8192;
    __syncthreads();             // drains the prefetch of THIS tile
    if (k0 + 32 < K) {           // prefetch next tile into the other buffer
      u16* nxt = lds + (buf ^ 1) * 8192;
      gload16(Ag0 + k0 + 32, nxt + lA0);
      gload16(Ag1 + k0 + 32, nxt + lA1);
      gload16(Wg0 + k0 + 32, nxt + lB0);
      gload16(Wg1 + k0 + 32, nxt + lB1);
    }

    bf16x8 af[4], bfr[4];
#pragma unroll
    for (int i = 0; i < 4; ++i) {
      af[i]  = *(const bf16x8*)(cur + (warp_m * 64 + i * 16 + l15) * 32 + quad * 8);
      bfr[i] = *(const bf16x8*)(cur + 4096 + (warp_n * 64 + i * 16 + l15) * 32 + quad * 8);
    }
#pragma unroll
    for (int i = 0; i < 4; ++i)
#pragma unroll
      for (int j = 0; j < 4; ++j)
        acc[i][j] = __builtin_amdgcn_mfma_f32_16x16x32_bf16(af[i], bfr[j], acc[i][j], 0, 0, 0);
  }
}

// QKV projection. 1-D grid of 768, XCD-aware decode: xcd = id&7; all 8 bn of a
// (bm,z) group share one XCD -> A-stripe + W stay in that XCD's 4MB L2.
//   z=0 -> Q [bh][s][d], prescaled by QSCALE (exp2-domain attention)
//   z=1 -> K [bh][s][d'] with d' chunk-swizzled by s&7  (conflict-free attn LDS reads)
//   z=2 -> V^T [bh][d][s'] with s' chunk-swizzled by d&7 within each 64-key group
__global__ __launch_bounds__(256) void gemm_qkv(
    const u16* __restrict__ qb, const u16* __restrict__ kb, const u16* __restrict__ vb,
    const u16* __restrict__ wq, const u16* __restrict__ wk, const u16* __restrict__ wv,
    u16* __restrict__ Qo, u16* __restrict__ Ko, u16* __restrict__ Vt) {
  __shared__ __align__(16) u16 lds[2][8192];
  const int id = blockIdx.x;
  const int c = id & 7, bn = (id >> 3) & 7, t = id >> 6;  // t in 0..11
  const int g = c + 8 * t;                                // 0..95
  const int bm = g & 31, z = g >> 5;

  const u16* A = (z == 0) ? qb : (z == 1) ? kb : vb;
  const u16* W = (z == 0) ? wq : (z == 1) ? wk : wv;
  f32x4 acc[4][4] = {};
  gemm128_core(A, W, bm, bn, &lds[0][0], acc);

  const int tid = threadIdx.x;
  const int wave = tid >> 6, lane = tid & 63;
  const int quad = lane >> 4, l15 = lane & 15;
  const int warp_m = wave >> 1, warp_n = wave & 1;
#pragma unroll
  for (int i = 0; i < 4; ++i)
#pragma unroll
    for (int j = 0; j < 4; ++j) {
      int s0 = bm * 128 + warp_m * 64 + i * 16 + quad * 4;  // token base (r adds 0..3)
      int n  = bn * 128 + warp_n * 64 + j * 16 + l15;       // out dim
      int bb = s0 >> 11, sl0 = s0 & 2047, h = n >> 6, d = n & 63;
      if (z == 2) {
        // pack 4 consecutive tokens (r=0..3) into one 8B store, key-chunk swizzled by d&7
        int ssw = (sl0 & ~63) | ((((sl0 >> 3) & 7) ^ (d & 7)) << 3) | (sl0 & 7);
        u16x4 pv;
        pv[0] = f2bf(acc[i][j][0]); pv[1] = f2bf(acc[i][j][1]);
        pv[2] = f2bf(acc[i][j][2]); pv[3] = f2bf(acc[i][j][3]);
        *(u16x4*)(Vt + ((size_t)(bb * NH + h) * HD + d) * SEQ + ssw) = pv;
      } else if (z == 1) {
#pragma unroll
        for (int r = 0; r < 4; ++r) {
          int s = sl0 + r;
          int dsw = (((d >> 3) ^ (s & 7)) << 3) | (d & 7);
          Ko[((size_t)(bb * NH + h) * SEQ + s) * HD + dsw] = f2bf(acc[i][j][r]);
        }
      } else {
#pragma unroll
        for (int r = 0; r < 4; ++r)
          Qo[((size_t)(bb * NH + h) * SEQ + sl0 + r) * HD + d] = f2bf(acc[i][j][r] * QSCALE);
      }
    }
}

// output projection: fp32 out = AO @ wo^T. 1-D grid of 256, XCD-aware decode.
__global__ __launch_bounds__(256) void gemm_out(
    const u16* __restrict__ A, const u16* __restrict__ W, float* __restrict__ Out) {
  __shared__ __align__(16) u16 lds[2][8192];
  const int id = blockIdx.x;
  const int bn = (id >> 3) & 7;
  const int bm = (id & 7) + 8 * (id >> 6);
  f32x4 acc[4][4] = {};
  gemm128_core(A, W, bm, bn, &lds[0][0], acc);

  const int tid = threadIdx.x;
  const int wave = tid >> 6, lane = tid & 63;
  const int quad = lane >> 4, l15 = lane & 15;
  const int warp_m = wave >> 1, warp_n = wave & 1;
#pragma unroll
  for (int i = 0; i < 4; ++i)
#pragma unroll
    for (int j = 0; j < 4; ++j)
#pragma unroll
      for (int r = 0; r < 4; ++r) {
        int m = bm * 128 + warp_m * 64 + i * 16 + quad * 4 + r;
        int n = bn * 128 + warp_n * 64 + j * 16 + l15;
        Out[(size_t)m * DIM + n] = acc[i][j][r];
      }
}

// ---------- flash attention (causal), S^T + O^T formulation ----------
// Q: [bh][s][d] bf16 (prescaled, exp2 domain); K: [bh][s][d-swz]; Vt: [bh][d][s-swz]
// block = 64 q-rows x one bh; wave w owns q rows qt*64 + w*16 + l15 (q on l15).
// S^T: C[key][q=l15]; O^T = V^T * P^T: C[d][q=l15] -> alpha/inv rescale is per-lane.

__global__ __launch_bounds__(256) void attn_kernel(
    const u16* __restrict__ Q, const u16* __restrict__ K,
    const u16* __restrict__ Vt, u16* __restrict__ O) {
  __shared__ __align__(16) u16 Kl[2][4096];    // [key][d'] swizzled, double-buffered
  __shared__ __align__(16) u16 Vl[2][4096];    // [d][key'] swizzled, double-buffered
  __shared__ __align__(16) u32 Plm[4][512];    // per-wave P^T: 16 q-rows x 32 dwords,
                                               // 16B blocks XOR-swizzled by l15&7
  const int tid = threadIdx.x;
  const int wave = tid >> 6, lane = tid & 63;
  const int quad = lane >> 4, l15 = lane & 15;
  const int bx = blockIdx.x;
  const int bh = bx & 31;
  const int qt = 31 - (bx >> 5);              // reversed: longest blocks first
  const int b = bh >> 4, h = bh & 15;

  // Q as B-operand: B[n=l15][k=quad*8+j], prescaled already
  const u16* qbase = Q + ((size_t)bh * SEQ + qt * 64 + wave * 16 + l15) * HD + quad * 8;
  const bf16x8 qf0 = *(const bf16x8*)(qbase);
  const bf16x8 qf1 = *(const bf16x8*)(qbase + 32);

  f32x4 o[4] = {};                            // O^T: o[n][r] = O[d=16n+4quad+r][q=l15]
  float l_sum = 0.f, m_run = NEG_INF;         // per-lane, q = l15 (dup across quads)

  const int c0 = wave * 128 + lane, c1 = c0 + 64;  // staging chunk ids (16B each)
  const u16* Ksrc = K + (size_t)bh * SEQ * HD;
  const u16* Vsrc = Vt + (size_t)bh * HD * SEQ;
  const int sw0 = ((quad ^ (l15 & 7)) << 3);       // swizzled chunk offsets for frag reads
  const int sw1 = (((4 + quad) ^ (l15 & 7)) << 3);

  // initial stage of tile 0 into buffer 0
  {
    gload16(Ksrc + (size_t)c0 * 8, &Kl[0][(wave * 2 + 0) * 512]);
    gload16(Ksrc + (size_t)c1 * 8, &Kl[0][(wave * 2 + 1) * 512]);
    gload16(Vsrc + (size_t)(c0 >> 3) * SEQ + (c0 & 7) * 8, &Vl[0][(wave * 2 + 0) * 512]);
    gload16(Vsrc + (size_t)(c1 >> 3) * SEQ + (c1 & 7) * 8, &Vl[0][(wave * 2 + 1) * 512]);
  }

  u32* prow = &Plm[wave][l15 * 32];
  const int psw = l15 & 7;                    // P 16B-block swizzle
  const int phalf = (quad & 1) * 2, pbhi = quad >> 1;

  for (int kt = 0; kt <= qt; ++kt) {
    const int buf = kt & 1;
    __syncthreads();   // drains stage(kt); all waves done reading buf from kt-1
    if (kt < qt) {     // prefetch tile kt+1 into the other buffer
      const int nb = buf ^ 1;
      const size_t kb = (size_t)(kt + 1) * 64;
      gload16(Ksrc + (kb * HD) + (size_t)c0 * 8, &Kl[nb][(wave * 2 + 0) * 512]);
      gload16(Ksrc + (kb * HD) + (size_t)c1 * 8, &Kl[nb][(wave * 2 + 1) * 512]);
      gload16(Vsrc + (size_t)(c0 >> 3) * SEQ + kb + (c0 & 7) * 8, &Vl[nb][(wave * 2 + 0) * 512]);
      gload16(Vsrc + (size_t)(c1 >> 3) * SEQ + kb + (c1 & 7) * 8, &Vl[nb][(wave * 2 + 1) * 512]);
    }

    // S^T = K Q^T : C[row=key local (kn*16 + quad*4 + r)][col=q=l15]
    f32x4 s[4];
#pragma unroll
    for (int kn = 0; kn < 4; ++kn) {
      const u16* arow = &Kl[buf][(kn * 16 + l15) * 64];
      bf16x8 kf0 = *(const bf16x8*)(arow + sw0);
      bf16x8 kf1 = *(const bf16x8*)(arow + sw1);
      f32x4 z = {};
      z = __builtin_amdgcn_mfma_f32_16x16x32_bf16(kf0, qf0, z, 0, 0, 0);
      z = __builtin_amdgcn_mfma_f32_16x16x32_bf16(kf1, qf1, z, 0, 0, 0);
      s[kn] = z;
    }

    if (kt == qt) {  // diagonal tile: mask key > q
      const int qloc = wave * 16 + l15;
#pragma unroll
      for (int kn = 0; kn < 4; ++kn)
#pragma unroll
        for (int r = 0; r < 4; ++r)
          if (kn * 16 + quad * 4 + r > qloc) s[kn][r] = NEG_INF;
    }

    // online softmax (exp2 domain): 16 in-lane values + 2 cross-quad shuffles
    float mr = NEG_INF;
#pragma unroll
    for (int kn = 0; kn < 4; ++kn)
#pragma unroll
      for (int r = 0; r < 4; ++r) mr = fmaxf(mr, s[kn][r]);
    mr = fmaxf(mr, __shfl_xor(mr, 16));
    mr = fmaxf(mr, __shfl_xor(mr, 32));
    const float mnew = fmaxf(m_run, mr);
    const float alpha = __builtin_amdgcn_exp2f(m_run - mnew);
    m_run = mnew;
    float rs = 0.f;
#pragma unroll
    for (int kn = 0; kn < 4; ++kn)
#pragma unroll
      for (int r = 0; r < 4; ++r) {
        float p = __builtin_amdgcn_exp2f(s[kn][r] - mnew);
        s[kn][r] = p;
        rs += p;
      }
    rs += __shfl_xor(rs, 16);
    rs += __shfl_xor(rs, 32);
    l_sum = l_sum * alpha + rs;

    // rescale O^T: every element has q=l15 -> plain per-lane multiply
#pragma unroll
    for (int n = 0; n < 4; ++n)
#pragma unroll
      for (int r = 0; r < 4; ++r) o[n][r] *= alpha;

    // P (bf16, packed cvt) -> per-wave LDS rows [q=l15][key], XOR-swizzled 16B blocks
#pragma unroll
    for (int kn = 0; kn < 4; ++kn) {
      u32x2 w;
      w[0] = pkbf(s[kn][0], s[kn][1]);
      w[1] = pkbf(s[kn][2], s[kn][3]);
      *(u32x2*)(prow + (((2 * kn + pbhi) ^ psw) << 2) + phalf) = w;
    }
    // reload as B-operand (P^T): B[n=q=l15][k=key quad*8+j], kk-th frag = keys 32kk..
    u32x4 t0 = *(const u32x4*)(prow + ((quad ^ psw) << 2));
    u32x4 t1 = *(const u32x4*)(prow + (((4 + quad) ^ psw) << 2));
    bf16x8 pf0 = __builtin_bit_cast(bf16x8, t0);
    bf16x8 pf1 = __builtin_bit_cast(bf16x8, t1);

    // O^T += V^T P^T : A = V^T (m=d), B = P^T (n=q), C[row=d quad*4+r+16n][col=q l15]
#pragma unroll
    for (int n = 0; n < 4; ++n) {
      const u16* vrow = &Vl[buf][(n * 16 + l15) * 64];
      bf16x8 vf0 = *(const bf16x8*)(vrow + sw0);
      bf16x8 vf1 = *(const bf16x8*)(vrow + sw1);
      o[n] = __builtin_amdgcn_mfma_f32_16x16x32_bf16(vf0, pf0, o[n], 0, 0, 0);
      o[n] = __builtin_amdgcn_mfma_f32_16x16x32_bf16(vf1, pf1, o[n], 0, 0, 0);
    }
  }

  // epilogue: O /= l (per-lane), write AO [b][s=q][h*64+d] as 8B stores
  const float inv = 1.f / l_sum;
  const int srow = qt * 64 + wave * 16 + l15;
  u16* obase = O + ((size_t)b * SEQ + srow) * DIM + h * HD + quad * 4;
#pragma unroll
  for (int n = 0; n < 4; ++n) {
    u32x2 st;
    st[0] = pkbf(o[n][0] * inv, o[n][1] * inv);
    st[1] = pkbf(o[n][2] * inv, o[n][3] * inv);
    *(u32x2*)(obase + n * 16) = st;
  }
}

// ---------- launch ----------

extern "C" void kernel_launch(void* const* d_in, const int* in_sizes, int n_in,
                              void* d_out, int out_size, void* d_ws, size_t ws_size,
                              hipStream_t stream) {
  (void)in_sizes; (void)n_in; (void)out_size; (void)ws_size;
  const float* q  = (const float*)d_in[0];
  const float* k  = (const float*)d_in[1];
  const float* v  = (const float*)d_in[2];
  const float* wq = (const float*)d_in[3];
  const float* wk = (const float*)d_in[4];
  const float* wv = (const float*)d_in[5];
  const float* wo = (const float*)d_in[6];

  u16* ws = (u16*)d_ws;
  const size_t EL = 1u << 20;
  u16* QB = ws + 0 * EL;
  u16* KB = ws + 4 * EL;
  u16* VB = ws + 8 * EL;
  u16* WQ = ws + 12 * EL;
  u16* WK = ws + 13 * EL;
  u16* WV = ws + 14 * EL;
  u16* WO = ws + 15 * EL;
  u16* Qw = ws + 16 * EL;   // Q  [bh][s][64] prescaled (exp2 domain)
  u16* Kw = ws + 20 * EL;   // K  [bh][s][64] swizzled
  u16* Vtw = ws + 24 * EL;  // V^T [bh][64][s] swizzled
  u16* AO = ws + 28 * EL;   // attn out [b][s][1024]

  cvt_all<<<8192, 256, 0, stream>>>(q, k, v, wq, wk, wv, wo, ws);
  gemm_qkv<<<768, 256, 0, stream>>>(QB, KB, VB, WQ, WK, WV, Qw, Kw, Vtw);
  attn_kernel<<<1024, 256, 0, stream>>>(Qw, Kw, Vtw, AO);
  gemm_out<<<256, 256, 0, stream>>>(AO, WO, (float*)d_out);
}

// Round 6
// 200.641 us; speedup vs baseline: 1.8339x; 1.0089x over previous
//
#include <hip/hip_runtime.h>

typedef unsigned short u16;
typedef unsigned int   u32;
typedef __bf16 bf16x8 __attribute__((ext_vector_type(8)));
typedef float  f32x4  __attribute__((ext_vector_type(4)));
typedef unsigned short u16x4 __attribute__((ext_vector_type(4)));
typedef unsigned short u16x8 __attribute__((ext_vector_type(8)));
typedef unsigned int   u32x2 __attribute__((ext_vector_type(2)));
typedef unsigned int   u32x4 __attribute__((ext_vector_type(4)));

#define DIM   1024
#define SEQ   2048
#define NH    16
#define HD    64
#define NBATCH 2

#define NEG_INF (-__builtin_inff())
// 0.125 * log2(e): Q pre-scale so attention works in exp2 domain
#define QSCALE 0.1803368801111204f

// ---------- helpers ----------

__device__ __forceinline__ u16 f2bf(float f) {
  unsigned u = __float_as_uint(f);
  unsigned r = (u + 0x7FFFu + ((u >> 16) & 1u)) >> 16;  // RNE
  return (u16)r;
}

// pack two f32 -> two bf16 in one dword (v_cvt_pk_bf16_f32 on gfx950)
__device__ __forceinline__ u32 pkbf(float a, float b) {
#if __has_builtin(__builtin_amdgcn_cvt_pk_bf16_f32)
  typedef __bf16 bf16x2 __attribute__((ext_vector_type(2)));
  bf16x2 t = __builtin_amdgcn_cvt_pk_bf16_f32(a, b);
  return __builtin_bit_cast(u32, t);
#else
  return (u32)f2bf(a) | ((u32)f2bf(b) << 16);
#endif
}

// async global->LDS, 16B per lane. lds dest must be wave-uniform base (+lane*16 by HW).
__device__ __forceinline__ void gload16(const void* g, void* lds_uniform) {
  __builtin_amdgcn_global_load_lds(
      (__attribute__((address_space(1))) void*)(size_t)g,
      (__attribute__((address_space(3))) void*)lds_uniform,
      16, 0, 0);
}

// ---------- fused fp32 -> bf16 convert for all 7 tensors ----------
// ws layout (u16 elems, M = 1<<20): QB@0, KB@4M, VB@8M, WQ@12M, WK@13M, WV@14M, WO@15M

__global__ __launch_bounds__(256) void cvt_all(
    const float* __restrict__ q, const float* __restrict__ k, const float* __restrict__ v,
    const float* __restrict__ wq, const float* __restrict__ wk, const float* __restrict__ wv,
    const float* __restrict__ wo, u16* __restrict__ ws) {
  const size_t M = 1u << 20;
  int b = blockIdx.x;
  const float* src;
  u16* dst;
  int idx;
  if (b < 6144) {           // q,k,v: 2048 blocks each (4M elems)
    int t = b >> 11; idx = b & 2047;
    src = (t == 0) ? q : (t == 1) ? k : v;
    dst = ws + (size_t)t * 4 * M;
  } else {                  // weights: 512 blocks each (1M elems)
    int t = (b - 6144) >> 9; idx = (b - 6144) & 511;
    src = (t == 0) ? wq : (t == 1) ? wk : (t == 2) ? wv : wo;
    dst = ws + (12 + (size_t)t) * M;
  }
  size_t i = ((size_t)idx * 256 + threadIdx.x) * 8;
  float4 a = *(const float4*)(src + i);
  float4 c = *(const float4*)(src + i + 4);
  u16x8 o;
  o[0] = f2bf(a.x); o[1] = f2bf(a.y); o[2] = f2bf(a.z); o[3] = f2bf(a.w);
  o[4] = f2bf(c.x); o[5] = f2bf(c.y); o[6] = f2bf(c.z); o[7] = f2bf(c.w);
  *(u16x8*)(dst + i) = o;
}

// ---------- GEMM core: C[m,n] = sum_k A[m,k]*W[n,k], 128x128 tile, BK=32 ----------
// Double-buffered LDS, ONE barrier per K-iter, prefetch issued right after the
// barrier so global_load_lds flies during the 16 MFMAs.

__device__ __forceinline__ void gemm128_core(const u16* __restrict__ A,
                                             const u16* __restrict__ W,
                                             int bm, int bn,
                                             u16* lds, f32x4 (&acc)[4][4]) {
  const int K = 1024;
  const int tid = threadIdx.x;
  const int wave = tid >> 6, lane = tid & 63;
  const int quad = lane >> 4, l15 = lane & 15;
  const int warp_m = wave >> 1, warp_n = wave & 1;

  const int c0 = wave * 128 + lane, c1 = c0 + 64;  // 16B chunk ids within tile
  const u16* Ag0 = A + (size_t)(bm * 128 + (c0 >> 2)) * K + (c0 & 3) * 8;
  const u16* Ag1 = A + (size_t)(bm * 128 + (c1 >> 2)) * K + (c1 & 3) * 8;
  const u16* Wg0 = W + (size_t)(bn * 128 + (c0 >> 2)) * K + (c0 & 3) * 8;
  const u16* Wg1 = W + (size_t)(bn * 128 + (c1 >> 2)) * K + (c1 & 3) * 8;
  const int lA0 = (wave * 2 + 0) * 512;
  const int lA1 = (wave * 2 + 1) * 512;
  const int lB0 = 4096 + (wave * 2 + 0) * 512;
  const int lB1 = 4096 + (wave * 2 + 1) * 512;

  // prologue: stage tile 0 into buffer 0
  gload16(Ag0, lds + lA0);
  gload16(Ag1, lds + lA1);
  gload16(Wg0, lds + lB0);
  gload16(Wg1, lds + lB1);

  for (int k0 = 0; k0 < K; k0 += 32) {
    const int buf = (k0 >> 5) & 1;
    u16* cur = lds + buf * 8192;
    __syncthreads();             // drains the prefetch of THIS tile
    if (k0 + 32 < K) {           // prefetch next tile into the other buffer
      u16* nxt = lds + (buf ^ 1) * 8192;
      gload16(Ag0 + k0 + 32, nxt + lA0);
      gload16(Ag1 + k0 + 32, nxt + lA1);
      gload16(Wg0 + k0 + 32, nxt + lB0);
      gload16(Wg1 + k0 + 32, nxt + lB1);
    }

    bf16x8 af[4], bfr[4];
#pragma unroll
    for (int i = 0; i < 4; ++i) {
      af[i]  = *(const bf16x8*)(cur + (warp_m * 64 + i * 16 + l15) * 32 + quad * 8);
      bfr[i] = *(const bf16x8*)(cur + 4096 + (warp_n * 64 + i * 16 + l15) * 32 + quad * 8);
    }
#pragma unroll
    for (int i = 0; i < 4; ++i)
#pragma unroll
      for (int j = 0; j < 4; ++j)
        acc[i][j] = __builtin_amdgcn_mfma_f32_16x16x32_bf16(af[i], bfr[j], acc[i][j], 0, 0, 0);
  }
}

// QKV projection. 1-D grid of 768, XCD-aware decode: xcd = id&7; all 8 bn of a
// (bm,z) group share one XCD -> A-stripe + W stay in that XCD's 4MB L2.
//   z=0 -> Q [bh][s][d], prescaled by QSCALE (exp2-domain attention)
//   z=1 -> K [bh][s][d'] with d' chunk-swizzled by s&7  (conflict-free attn LDS reads)
//   z=2 -> V^T [bh][d][pos'] with key->pos bit-permuted to match the lane-local
//          P fragment order (pos = kk|q|h|r from key = kk|h|q|r), then chunk-
//          swizzled by d&7. Attn-side reads are identical to the K pattern.
__global__ __launch_bounds__(256) void gemm_qkv(
    const u16* __restrict__ qb, const u16* __restrict__ kb, const u16* __restrict__ vb,
    const u16* __restrict__ wq, const u16* __restrict__ wk, const u16* __restrict__ wv,
    u16* __restrict__ Qo, u16* __restrict__ Ko, u16* __restrict__ Vt) {
  __shared__ __align__(16) u16 lds[2][8192];
  const int id = blockIdx.x;
  const int c = id & 7, bn = (id >> 3) & 7, t = id >> 6;  // t in 0..11
  const int g = c + 8 * t;                                // 0..95
  const int bm = g & 31, z = g >> 5;

  const u16* A = (z == 0) ? qb : (z == 1) ? kb : vb;
  const u16* W = (z == 0) ? wq : (z == 1) ? wk : wv;
  f32x4 acc[4][4] = {};
  gemm128_core(A, W, bm, bn, &lds[0][0], acc);

  const int tid = threadIdx.x;
  const int wave = tid >> 6, lane = tid & 63;
  const int quad = lane >> 4, l15 = lane & 15;
  const int warp_m = wave >> 1, warp_n = wave & 1;
#pragma unroll
  for (int i = 0; i < 4; ++i)
#pragma unroll
    for (int j = 0; j < 4; ++j) {
      int s0 = bm * 128 + warp_m * 64 + i * 16 + quad * 4;  // token base (r adds 0..3)
      int n  = bn * 128 + warp_n * 64 + j * 16 + l15;       // out dim
      int bb = s0 >> 11, sl0 = s0 & 2047, h = n >> 6, d = n & 63;
      if (z == 2) {
        // key -> position bit permutation within the 64-key group:
        //   key bits [kk(5)|h(4)|q(3:2)|r(1:0)] -> pos [kk(5)|q(4:3)|h(2)|r(1:0)]
        int pos = (sl0 & ~63) | (sl0 & 32) | ((sl0 & 12) << 1) | ((sl0 & 16) >> 2);
        // then 8-elem chunk swizzle by d&7 (r stays in bits 1:0 -> 4 tokens contiguous)
        int psw = (pos & ~63) | ((((pos >> 3) & 7) ^ (d & 7)) << 3) | (pos & 7);
        u16x4 pv;
        pv[0] = f2bf(acc[i][j][0]); pv[1] = f2bf(acc[i][j][1]);
        pv[2] = f2bf(acc[i][j][2]); pv[3] = f2bf(acc[i][j][3]);
        *(u16x4*)(Vt + ((size_t)(bb * NH + h) * HD + d) * SEQ + psw) = pv;
      } else if (z == 1) {
#pragma unroll
        for (int r = 0; r < 4; ++r) {
          int s = sl0 + r;
          int dsw = (((d >> 3) ^ (s & 7)) << 3) | (d & 7);
          Ko[((size_t)(bb * NH + h) * SEQ + s) * HD + dsw] = f2bf(acc[i][j][r]);
        }
      } else {
#pragma unroll
        for (int r = 0; r < 4; ++r)
          Qo[((size_t)(bb * NH + h) * SEQ + sl0 + r) * HD + d] = f2bf(acc[i][j][r] * QSCALE);
      }
    }
}

// output projection: fp32 out = AO @ wo^T. 1-D grid of 256, XCD-aware decode.
__global__ __launch_bounds__(256) void gemm_out(
    const u16* __restrict__ A, const u16* __restrict__ W, float* __restrict__ Out) {
  __shared__ __align__(16) u16 lds[2][8192];
  const int id = blockIdx.x;
  const int bn = (id >> 3) & 7;
  const int bm = (id & 7) + 8 * (id >> 6);
  f32x4 acc[4][4] = {};
  gemm128_core(A, W, bm, bn, &lds[0][0], acc);

  const int tid = threadIdx.x;
  const int wave = tid >> 6, lane = tid & 63;
  const int quad = lane >> 4, l15 = lane & 15;
  const int warp_m = wave >> 1, warp_n = wave & 1;
#pragma unroll
  for (int i = 0; i < 4; ++i)
#pragma unroll
    for (int j = 0; j < 4; ++j)
#pragma unroll
      for (int r = 0; r < 4; ++r) {
        int m = bm * 128 + warp_m * 64 + i * 16 + quad * 4 + r;
        int n = bn * 128 + warp_n * 64 + j * 16 + l15;
        Out[(size_t)m * DIM + n] = acc[i][j][r];
      }
}

// ---------- flash attention (causal), S^T + O^T formulation ----------
// Q: [bh][s][d] bf16 (prescaled, exp2 domain); K: [bh][s][d-swz]; Vt: [bh][d][pos-swz]
// block = 64 q-rows x one bh; wave w owns q rows qt*64 + w*16 + l15 (q on l15).
// S^T: C[key][q=l15]; O^T = V^T P^T: C[d][q=l15] -> alpha/inv rescale is per-lane.
// P B-operand is LANE-LOCAL: the MFMA k-dim key order is chosen to match the S^T
// C-layout (key = 32kk+16h+4quad+r at k-pos quad*8+4h+r); V was stored with the
// same permutation, so its LDS reads keep the standard swizzled-b128 pattern.
// l_sum folded into PV via ones-A-fragment MFMA (o4 accumulator).

__global__ __launch_bounds__(256) void attn_kernel(
    const u16* __restrict__ Q, const u16* __restrict__ K,
    const u16* __restrict__ Vt, u16* __restrict__ O) {
  __shared__ __align__(16) u16 Kl[2][4096];    // [key][d'] swizzled, double-buffered
  __shared__ __align__(16) u16 Vl[2][4096];    // [d][pos'] swizzled, double-buffered
  // total LDS 32768 B -> 5 blocks/CU

  const int tid = threadIdx.x;
  const int wave = tid >> 6, lane = tid & 63;
  const int quad = lane >> 4, l15 = lane & 15;
  const int bx = blockIdx.x;
  const int bh = bx & 31;
  const int qt = 31 - (bx >> 5);              // reversed: longest blocks first
  const int b = bh >> 4, h = bh & 15;

  // Q as B-operand: B[n=l15][k=quad*8+j], prescaled already
  const u16* qbase = Q + ((size_t)bh * SEQ + qt * 64 + wave * 16 + l15) * HD + quad * 8;
  const bf16x8 qf0 = *(const bf16x8*)(qbase);
  const bf16x8 qf1 = *(const bf16x8*)(qbase + 32);

  bf16x8 ones;
#pragma unroll
  for (int i = 0; i < 8; ++i) ones[i] = (__bf16)1.0f;

  f32x4 o[4] = {};                            // O^T: o[n][r] = O[d=16n+4quad+r][q=l15]
  f32x4 o4 = {};                              // ones-row: every elem = running l_sum
  float m_run = NEG_INF;                      // per-lane, q = l15 (dup across quads)

  const int c0 = wave * 128 + lane, c1 = c0 + 64;  // staging chunk ids (16B each)
  const u16* Ksrc = K + (size_t)bh * SEQ * HD;
  const u16* Vsrc = Vt + (size_t)bh * HD * SEQ;
  const int sw0 = ((quad ^ (l15 & 7)) << 3);       // swizzled chunk offsets for frag reads
  const int sw1 = (((4 + quad) ^ (l15 & 7)) << 3);

  // initial stage of tile 0 into buffer 0
  {
    gload16(Ksrc + (size_t)c0 * 8, &Kl[0][(wave * 2 + 0) * 512]);
    gload16(Ksrc + (size_t)c1 * 8, &Kl[0][(wave * 2 + 1) * 512]);
    gload16(Vsrc + (size_t)(c0 >> 3) * SEQ + (c0 & 7) * 8, &Vl[0][(wave * 2 + 0) * 512]);
    gload16(Vsrc + (size_t)(c1 >> 3) * SEQ + (c1 & 7) * 8, &Vl[0][(wave * 2 + 1) * 512]);
  }

  for (int kt = 0; kt <= qt; ++kt) {
    const int buf = kt & 1;
    __syncthreads();   // drains stage(kt); all waves done reading buf from kt-1
    if (kt < qt) {     // prefetch tile kt+1 into the other buffer
      const int nb = buf ^ 1;
      const size_t kb = (size_t)(kt + 1) * 64;
      gload16(Ksrc + (kb * HD) + (size_t)c0 * 8, &Kl[nb][(wave * 2 + 0) * 512]);
      gload16(Ksrc + (kb * HD) + (size_t)c1 * 8, &Kl[nb][(wave * 2 + 1) * 512]);
      gload16(Vsrc + (size_t)(c0 >> 3) * SEQ + kb + (c0 & 7) * 8, &Vl[nb][(wave * 2 + 0) * 512]);
      gload16(Vsrc + (size_t)(c1 >> 3) * SEQ + kb + (c1 & 7) * 8, &Vl[nb][(wave * 2 + 1) * 512]);
    }

    // S^T = K Q^T : C[row=key local (kn*16 + quad*4 + r)][col=q=l15]
    f32x4 s[4];
#pragma unroll
    for (int kn = 0; kn < 4; ++kn) {
      const u16* arow = &Kl[buf][(kn * 16 + l15) * 64];
      bf16x8 kf0 = *(const bf16x8*)(arow + sw0);
      bf16x8 kf1 = *(const bf16x8*)(arow + sw1);
      f32x4 z = {};
      z = __builtin_amdgcn_mfma_f32_16x16x32_bf16(kf0, qf0, z, 0, 0, 0);
      z = __builtin_amdgcn_mfma_f32_16x16x32_bf16(kf1, qf1, z, 0, 0, 0);
      s[kn] = z;
    }

    if (kt == qt) {  // diagonal tile: mask key > q
      const int qloc = wave * 16 + l15;
#pragma unroll
      for (int kn = 0; kn < 4; ++kn)
#pragma unroll
        for (int r = 0; r < 4; ++r)
          if (kn * 16 + quad * 4 + r > qloc) s[kn][r] = NEG_INF;
    }

    // online softmax max (exp2 domain): 16 in-lane values + 2 cross-quad shuffles
    float mr = NEG_INF;
#pragma unroll
    for (int kn = 0; kn < 4; ++kn)
#pragma unroll
      for (int r = 0; r < 4; ++r) mr = fmaxf(mr, s[kn][r]);
    mr = fmaxf(mr, __shfl_xor(mr, 16));
    mr = fmaxf(mr, __shfl_xor(mr, 32));
    const float mnew = fmaxf(m_run, mr);
    const float alpha = __builtin_amdgcn_exp2f(m_run - mnew);
    m_run = mnew;
#pragma unroll
    for (int kn = 0; kn < 4; ++kn)
#pragma unroll
      for (int r = 0; r < 4; ++r)
        s[kn][r] = __builtin_amdgcn_exp2f(s[kn][r] - mnew);

    // P B-operand fragments are lane-local under the permuted key order:
    // frag kk elements j = {kn=2kk (r0..3), kn=2kk+1 (r0..3)}
    u32x4 t0, t1;
    t0[0] = pkbf(s[0][0], s[0][1]); t0[1] = pkbf(s[0][2], s[0][3]);
    t0[2] = pkbf(s[1][0], s[1][1]); t0[3] = pkbf(s[1][2], s[1][3]);
    t1[0] = pkbf(s[2][0], s[2][1]); t1[1] = pkbf(s[2][2], s[2][3]);
    t1[2] = pkbf(s[3][0], s[3][1]); t1[3] = pkbf(s[3][2], s[3][3]);
    bf16x8 pf0 = __builtin_bit_cast(bf16x8, t0);
    bf16x8 pf1 = __builtin_bit_cast(bf16x8, t1);

    // rescale accumulators (per-lane: every element has q=l15)
#pragma unroll
    for (int n = 0; n < 4; ++n)
#pragma unroll
      for (int r = 0; r < 4; ++r) o[n][r] *= alpha;
#pragma unroll
    for (int r = 0; r < 4; ++r) o4[r] *= alpha;

    // l_sum via ones-fragment MFMA: every row of o4 = sum over 64 keys of P[.][q]
    o4 = __builtin_amdgcn_mfma_f32_16x16x32_bf16(ones, pf0, o4, 0, 0, 0);
    o4 = __builtin_amdgcn_mfma_f32_16x16x32_bf16(ones, pf1, o4, 0, 0, 0);

    // O^T += V^T P^T : A = V^T (m=d), B = P^T (n=q), C[row=d quad*4+r+16n][col=q l15]
#pragma unroll
    for (int n = 0; n < 4; ++n) {
      const u16* vrow = &Vl[buf][(n * 16 + l15) * 64];
      bf16x8 vf0 = *(const bf16x8*)(vrow + sw0);
      bf16x8 vf1 = *(const bf16x8*)(vrow + sw1);
      o[n] = __builtin_amdgcn_mfma_f32_16x16x32_bf16(vf0, pf0, o[n], 0, 0, 0);
      o[n] = __builtin_amdgcn_mfma_f32_16x16x32_bf16(vf1, pf1, o[n], 0, 0, 0);
    }
  }

  // epilogue: O /= l (per-lane), write AO [b][s=q][h*64+d] as 8B stores
  const float inv = 1.f / o4[0];
  const int srow = qt * 64 + wave * 16 + l15;
  u16* obase = O + ((size_t)b * SEQ + srow) * DIM + h * HD + quad * 4;
#pragma unroll
  for (int n = 0; n < 4; ++n) {
    u32x2 st;
    st[0] = pkbf(o[n][0] * inv, o[n][1] * inv);
    st[1] = pkbf(o[n][2] * inv, o[n][3] * inv);
    *(u32x2*)(obase + n * 16) = st;
  }
}

// ---------- launch ----------

extern "C" void kernel_launch(void* const* d_in, const int* in_sizes, int n_in,
                              void* d_out, int out_size, void* d_ws, size_t ws_size,
                              hipStream_t stream) {
  (void)in_sizes; (void)n_in; (void)out_size; (void)ws_size;
  const float* q  = (const float*)d_in[0];
  const float* k  = (const float*)d_in[1];
  const float* v  = (const float*)d_in[2];
  const float* wq = (const float*)d_in[3];
  const float* wk = (const float*)d_in[4];
  const float* wv = (const float*)d_in[5];
  const float* wo = (const float*)d_in[6];

  u16* ws = (u16*)d_ws;
  const size_t EL = 1u << 20;
  u16* QB = ws + 0 * EL;
  u16* KB = ws + 4 * EL;
  u16* VB = ws + 8 * EL;
  u16* WQ = ws + 12 * EL;
  u16* WK = ws + 13 * EL;
  u16* WV = ws + 14 * EL;
  u16* WO = ws + 15 * EL;
  u16* Qw = ws + 16 * EL;   // Q  [bh][s][64] prescaled (exp2 domain)
  u16* Kw = ws + 20 * EL;   // K  [bh][s][64] swizzled
  u16* Vtw = ws + 24 * EL;  // V^T [bh][64][pos] permuted+swizzled
  u16* AO = ws + 28 * EL;   // attn out [b][s][1024]

  cvt_all<<<8192, 256, 0, stream>>>(q, k, v, wq, wk, wv, wo, ws);
  gemm_qkv<<<768, 256, 0, stream>>>(QB, KB, VB, WQ, WK, WV, Qw, Kw, Vtw);
  attn_kernel<<<1024, 256, 0, stream>>>(Qw, Kw, Vtw, AO);
  gemm_out<<<256, 256, 0, stream>>>(AO, WO, (float*)d_out);
}